// Round 1
// baseline (3540.003 us; speedup 1.0000x reference)
//
#include <hip/hip_runtime.h>

// GraphNeuralNetwork: 4 layers of gather(src)*w -> scatter_add(dst) -> +bias -> relu
// B=256 batch, N=8192 neurons, E=262144 edges/layer, fp32.
// Strategy (round 0): transposed [N,B] activation layout; one wave per edge
// (64 lanes x float4 = 256 batch elems); native fp32 atomics for scatter.

static constexpr int BATCH = 256;
static constexpr int NN    = 8192;
static constexpr int NE    = 262144;
static constexpr int NL    = 4;

// Generic 32x32 LDS tile transpose: in is [R,C], out is [C,R].
__global__ void transpose_k(const float* __restrict__ in, float* __restrict__ out,
                            int R, int C) {
  __shared__ float tile[32][33];
  int c0 = blockIdx.x * 32, r0 = blockIdx.y * 32;
  int tx = threadIdx.x, ty = threadIdx.y;
#pragma unroll
  for (int i = ty; i < 32; i += 8)
    tile[i][tx] = in[(size_t)(r0 + i) * C + (c0 + tx)];
  __syncthreads();
#pragma unroll
  for (int i = ty; i < 32; i += 8)
    out[(size_t)(c0 + i) * R + (r0 + tx)] = tile[tx][i];
}

// acc[n*B + b] = bias[n]  (folds the bias add into accumulator init)
__global__ void init_bias_k(float* __restrict__ acc, const float* __restrict__ bias) {
  int i = blockIdx.x * blockDim.x + threadIdx.x;
  acc[i] = bias[i >> 8];  // i/256 = neuron index
}

// One wave per edge: lane L holds batch elems 4L..4L+3 as float4.
// Gather act[src][:], scale by w, atomic-add into acc[dst][:].
__global__ void scatter_k(const float* __restrict__ act, float* __restrict__ acc,
                          const int* __restrict__ src, const int* __restrict__ dst,
                          const float* __restrict__ w) {
  int e    = blockIdx.x * 4 + (threadIdx.x >> 6);  // 4 waves/block, 1 edge/wave
  int lane = threadIdx.x & 63;
  int   s  = src[e];
  int   d  = dst[e];
  float wt = w[e];
  float4 v = ((const float4*)(act + (size_t)s * BATCH))[lane];
  float* p = acc + (size_t)d * BATCH + lane * 4;
  unsafeAtomicAdd(p + 0, v.x * wt);
  unsafeAtomicAdd(p + 1, v.y * wt);
  unsafeAtomicAdd(p + 2, v.z * wt);
  unsafeAtomicAdd(p + 3, v.w * wt);
}

__global__ void relu_k(float* __restrict__ a) {
  int i = blockIdx.x * blockDim.x + threadIdx.x;
  a[i] = fmaxf(a[i], 0.f);
}

extern "C" void kernel_launch(void* const* d_in, const int* in_sizes, int n_in,
                              void* d_out, int out_size, void* d_ws, size_t ws_size,
                              hipStream_t stream) {
  const float* x       = (const float*)d_in[0];  // [B, N]
  const float* weights = (const float*)d_in[1];  // [L, E]
  const float* bias    = (const float*)d_in[2];  // [L, N]
  const int*   esrc    = (const int*)d_in[3];    // [L, E]
  const int*   edst    = (const int*)d_in[4];    // [L, E]
  float*       out     = (float*)d_out;          // [B, N]

  float* actA = (float*)d_ws;                    // [N, B] current activations
  float* actB = actA + (size_t)NN * BATCH;       // [N, B] accumulator / next

  dim3 tb(32, 8);
  // x [B,N] -> actA [N,B]
  transpose_k<<<dim3(NN / 32, BATCH / 32), tb, 0, stream>>>(x, actA, BATCH, NN);

  for (int l = 0; l < NL; ++l) {
    init_bias_k<<<(NN * BATCH) / 256, 256, 0, stream>>>(actB, bias + (size_t)l * NN);
    scatter_k<<<NE / 4, 256, 0, stream>>>(actA, actB,
                                          esrc + (size_t)l * NE,
                                          edst + (size_t)l * NE,
                                          weights + (size_t)l * NE);
    relu_k<<<(NN * BATCH) / 256, 256, 0, stream>>>(actB);
    float* t = actA; actA = actB; actB = t;
  }

  // actA [N,B] -> out [B,N]
  transpose_k<<<dim3(BATCH / 32, NN / 32), tb, 0, stream>>>(actA, out, NN, BATCH);
}

// Round 2
// 235.190 us; speedup vs baseline: 15.0517x; 15.0517x over previous
//
#include <hip/hip_runtime.h>

// GraphNeuralNetwork: 4 layers of gather(src)*w -> scatter_add(dst) -> +bias -> relu
// B=256, N=8192, E=262144 (2^18), fp32.
// Round 1: replace atomic scatter (atomic-bound, 875us/layer) with dst-CSR gather.
// CSR built on-device every call (deterministic work; bucket order atomic-racy but
// fp32 sum-order noise ~1e-7 << threshold). Bias+ReLU fused into gather kernel.

static constexpr int BATCH = 256;
static constexpr int NN    = 8192;
static constexpr int NE    = 262144;   // 2^18
static constexpr int NL    = 4;
static constexpr int LOG2E = 18;

// ---- 32x32 LDS tile transpose: in [R,C] -> out [C,R] ----
__global__ void transpose_k(const float* __restrict__ in, float* __restrict__ out,
                            int R, int C) {
  __shared__ float tile[32][33];
  int c0 = blockIdx.x * 32, r0 = blockIdx.y * 32;
  int tx = threadIdx.x, ty = threadIdx.y;
#pragma unroll
  for (int i = ty; i < 32; i += 8)
    tile[i][tx] = in[(size_t)(r0 + i) * C + (c0 + tx)];
  __syncthreads();
#pragma unroll
  for (int i = ty; i < 32; i += 8)
    out[(size_t)(c0 + i) * R + (r0 + tx)] = tile[tx][i];
}

// ---- CSR build: histogram over dst (all L*E edges) ----
__global__ void hist_k(const int* __restrict__ dst, int* __restrict__ hist) {
  int i = blockIdx.x * 256 + threadIdx.x;   // [0, NL*NE)
  int l = i >> LOG2E;
  atomicAdd(&hist[l * NN + dst[i]], 1);
}

// ---- exclusive scan per layer (1 block of 256 threads per layer) ----
__global__ void scan_k(const int* __restrict__ hist, int* __restrict__ row_ptr,
                       int* __restrict__ cursor) {
  int l = blockIdx.x;
  int t = threadIdx.x;
  const int per = NN / 256;  // 32 counts per thread
  __shared__ int part[256];
  int base = l * NN + t * per;
  int s = 0;
  for (int k = 0; k < per; ++k) s += hist[base + k];
  part[t] = s;
  __syncthreads();
  for (int off = 1; off < 256; off <<= 1) {  // Hillis-Steele inclusive scan
    int v = (t >= off) ? part[t - off] : 0;
    __syncthreads();
    part[t] += v;
    __syncthreads();
  }
  int run = (t == 0) ? 0 : part[t - 1];      // exclusive base
  int rp_base = l * (NN + 1) + t * per;
  for (int k = 0; k < per; ++k) {
    row_ptr[rp_base + k] = run;
    cursor[base + k]     = run;
    run += hist[base + k];
  }
  if (t == 255) row_ptr[l * (NN + 1) + NN] = run;  // == NE
}

// ---- bucket fill: csr[l][p] = (src_bits, w) ----
__global__ void fill_k(const int* __restrict__ src, const int* __restrict__ dst,
                       const float* __restrict__ w, int* __restrict__ cursor,
                       float2* __restrict__ csr) {
  int i = blockIdx.x * 256 + threadIdx.x;   // [0, NL*NE)
  int l = i >> LOG2E;
  int p = atomicAdd(&cursor[l * NN + dst[i]], 1);
  csr[((size_t)l << LOG2E) + p] = make_float2(__int_as_float(src[i]), w[i]);
}

// ---- per-layer gather: one wave per dst row; fused bias + relu ----
__global__ void gather_k(const float* __restrict__ act, float* __restrict__ out,
                         const float2* __restrict__ csr, const int* __restrict__ rp,
                         const float* __restrict__ bias) {
  int row  = blockIdx.x * 4 + (threadIdx.x >> 6);  // 4 waves/block
  int lane = threadIdx.x & 63;
  int k0 = rp[row], k1 = rp[row + 1];
  float b = bias[row];
  float4 acc = make_float4(b, b, b, b);
  for (int k = k0; k < k1; ++k) {
    float2 m = csr[k];                   // broadcast (same addr all lanes)
    int   s  = __float_as_int(m.x);
    float wt = m.y;
    float4 v = ((const float4*)(act + (size_t)s * BATCH))[lane];
    acc.x += wt * v.x; acc.y += wt * v.y; acc.z += wt * v.z; acc.w += wt * v.w;
  }
  float4 r = make_float4(fmaxf(acc.x, 0.f), fmaxf(acc.y, 0.f),
                         fmaxf(acc.z, 0.f), fmaxf(acc.w, 0.f));
  ((float4*)(out + (size_t)row * BATCH))[lane] = r;
}

extern "C" void kernel_launch(void* const* d_in, const int* in_sizes, int n_in,
                              void* d_out, int out_size, void* d_ws, size_t ws_size,
                              hipStream_t stream) {
  const float* x       = (const float*)d_in[0];  // [B, N]
  const float* weights = (const float*)d_in[1];  // [L, E]
  const float* bias    = (const float*)d_in[2];  // [L, N]
  const int*   esrc    = (const int*)d_in[3];    // [L, E]
  const int*   edst    = (const int*)d_in[4];    // [L, E]
  float*       out     = (float*)d_out;          // [B, N]

  // workspace layout
  char* p = (char*)d_ws;
  float*  actA    = (float*)p;  p += (size_t)NN * BATCH * 4;      // 8 MB
  float*  actB    = (float*)p;  p += (size_t)NN * BATCH * 4;      // 8 MB
  float2* csr     = (float2*)p; p += (size_t)NL * NE * 8;         // 8 MB
  int*    row_ptr = (int*)p;    p += (size_t)NL * (NN + 1) * 4;
  int*    cursor  = (int*)p;    p += (size_t)NL * NN * 4;
  int*    hist    = (int*)p;    p += (size_t)NL * NN * 4;

  dim3 tb(32, 8);
  // x [B,N] -> actA [N,B]
  transpose_k<<<dim3(NN / 32, BATCH / 32), tb, 0, stream>>>(x, actA, BATCH, NN);

  // build per-layer dst-CSR
  hipMemsetAsync(hist, 0, (size_t)NL * NN * 4, stream);
  hist_k<<<(NL * NE) / 256, 256, 0, stream>>>(edst, hist);
  scan_k<<<NL, 256, 0, stream>>>(hist, row_ptr, cursor);
  fill_k<<<(NL * NE) / 256, 256, 0, stream>>>(esrc, edst, weights, cursor, csr);

  for (int l = 0; l < NL; ++l) {
    gather_k<<<NN / 4, 256, 0, stream>>>(actA, actB,
                                         csr + (size_t)l * NE,
                                         row_ptr + (size_t)l * (NN + 1),
                                         bias + (size_t)l * NN);
    float* t = actA; actA = actB; actB = t;
  }

  // actA [N,B] -> out [B,N]
  transpose_k<<<dim3(BATCH / 32, NN / 32), tb, 0, stream>>>(actA, out, NN, BATCH);
}